// Round 5
// baseline (122.116 us; speedup 1.0000x reference)
//
#include <hip/hip_runtime.h>
#include <math.h>

#define NB 20000
#define SPIN 365
#define TRAINLEN 15000
#define ML_C 2.9086f
#define SL_C 1.898f

// speculative decoupling: each lane owns CHUNK steps after WSPEC warm-up from
// speculated c=0. absmax identical (9.77e-4) at W=128 and W=96 => spec error
// at W=96 is below the fp32-vs-np rounding floor; threshold 2.45e-2.
#define CHUNK 8
#define WSPEC 96
#define TSTEPS (WSPEC + CHUNK)
#define NLANES 2500          // NB / CHUNK
#define NSCANBLK 40          // 40*64 = 2560 lanes >= 2500
#define WIN 608              // per-block x window: 512 owned + 96 warm-up
#define PWIN 684             // padded LDS plane size: WIN + WIN/8

#define EX2(x) __builtin_amdgcn_exp2f(x)
#define RCP(x) __builtin_amdgcn_rcpf(x)
#define L2E 1.4426950408889634f

__device__ __forceinline__ int clampi(int j) {
  return j < 0 ? 0 : (j > NB - 1 ? NB - 1 : j);
}

__global__ __launch_bounds__(64) void fused_kernel(
    const float* __restrict__ x, const float* __restrict__ y,
    const float* __restrict__ p_mean, const float* __restrict__ p_std,
    const int* __restrict__ time_lag,
    const float* __restrict__ w_r_yom, const float* __restrict__ w_r_yom_fp,
    const float* __restrict__ w_r_yom_gw, const float* __restrict__ w_r_ylm,
    const float* __restrict__ w_r_yfm,
    const float* __restrict__ w_b1_yom, const float* __restrict__ w_b1_yom_gw,
    const float* __restrict__ w_b1_yom_fp, const float* __restrict__ w_b2_ylm,
    const float* __restrict__ theltaC,
    const float* __restrict__ b0_yom, const float* __restrict__ b0_yom_gw,
    const float* __restrict__ b0_yom_fp, const float* __restrict__ b0_ylm,
    float* __restrict__ out) {
  const int lane = threadIdx.x;
  const int tl = time_lag[0];

  if (blockIdx.x == NSCANBLK) {
    // ---------- obsstd block: std(y[SPIN:TRAINLEN], ddof=1) ----------
    double a = 0.0, q = 0.0;
    if (lane < 3) {                       // head: 365..367 (float4 align at 368)
      double v = (double)y[SPIN + lane];
      a += v; q += v * v;
    }
    const float4* y4 = (const float4*)(y + 368);   // 368..14999 = 3658 float4
    for (int i = lane; i < 3658; i += 64) {
      float4 v = y4[i];
      double v0 = v.x, v1 = v.y, v2 = v.z, v3 = v.w;
      a += v0 + v1 + v2 + v3;
      q += v0 * v0 + v1 * v1 + v2 * v2 + v3 * v3;
    }
    for (int off = 32; off > 0; off >>= 1) {       // 64-lane double butterfly
      a += __shfl_xor(a, off, 64);
      q += __shfl_xor(q, off, 64);
    }
    const double n = (double)(TRAINLEN - SPIN);
    const float sd = (float)sqrt((q - a * a / n) / (n - 1.0));
    // obs_std column (contiguous float4)
    for (int i = lane; i < NB / 4; i += 64) {
      int t = 4 * i;
      float4 v;
      v.x = (t >= tl) ? sd : 0.f;
      v.y = (t + 1 >= tl) ? sd : 0.f;
      v.z = (t + 2 >= tl) ? sd : 0.f;
      v.w = (t + 3 >= tl) ? sd : 0.f;
      *(float4*)(out + 16 * NB + t) = v;
    }
    // h_nout odd slots (sd part); even slots owned by scan blocks — disjoint
    for (int t = lane; t < NB; t += 64)
      out[14 * NB + 2 * t + 1] = (t >= tl) ? sd : 0.f;
    return;
  }

  // ---------- scan blocks ----------
  const int gid = blockIdx.x * 64 + lane;
  const int start = gid * CHUNK;
  const int begin = start - WSPEC;

  // ---- stage this block's x window into LDS, coalesced ----
  // window = [blk*512 - WSPEC, blk*512 + 512), clamped; pad 1 word per 8 so
  // per-step lane stride is 9 words -> all 32 banks, 2-way alias (free).
  __shared__ float su1[PWIN];
  __shared__ float su2[PWIN];
  {
    const float2* __restrict__ xv = (const float2*)x;
    const int wstart = blockIdx.x * 512 - WSPEC;
    for (int j = lane; j < WIN; j += 64) {
      float2 v = xv[clampi(wstart + j)];
      int p = j + (j >> 3);
      su1[p] = v.x;
      su2[p] = v.y;
    }
  }
  __syncthreads();

  // fold parameters into per-step constants
  float e1 = __expf(w_r_yom[0]);
  float e2 = __expf(w_r_yom_gw[0]);
  float e3 = __expf(w_r_ylm[0]);
  float e4 = __expf(w_r_yfm[0]);
  float e5 = __expf(w_r_yom_fp[0]);
  float rd = 1.f / (e1 + e2 + e3 + e4 + e5);
  float oo1 = e1 * rd, oogw1 = e2 * rd, oofp1 = e5 * rd, ol1 = e3 * rd;
  float expC = __expf(theltaC[0]);
  float mo = p_mean[0];
  float inv_so = 1.f / p_std[0];
  float w1 = w_b1_yom[0], w1gw = w_b1_yom_gw[0], w1fp = w_b1_yom_fp[0], w2 = w_b2_ylm[0];
  float k_oo = -L2E * (w1 * inv_so);
  float d_oo = -L2E * (b0_yom[0] - mo * inv_so * w1);
  float k_gw = -L2E * (w1gw * inv_so);
  float d_gw = -L2E * (b0_yom_gw[0] - mo * inv_so * w1gw);
  float k_fp = -L2E * (w1fp * inv_so);
  float d_fp = -L2E * (b0_yom_fp[0] - mo * inv_so * w1fp);
  float k_ol = -L2E * (w2 / SL_C);
  float d_ol = -L2E * (b0_ylm[0] - (ML_C / SL_C) * w2);

  const int lb = lane * 9;   // lane's padded LDS base (element j = lane*8+t)

  float c = 0.f;
  // ---- warm-up: t = 0..WSPEC-1, no stores ----
  for (int tt = 0; tt < WSPEC; tt += 8) {
#pragma unroll
    for (int k = 0; k < 8; ++k) {
      const int t = tt + k;
      const int idx = begin + t;
      const int p = lb + t + (t >> 3);
      float u1 = su1[p], u2 = su2[p];
      if (idx >= 0) {   // divergent only in block 0's first iterations
        float px = fmaxf(u1 + c - expC, 0.f);
        float soo = RCP(1.f + EX2(fmaf(c, k_oo, d_oo)));
        float sgw = RCP(1.f + EX2(fmaf(c, k_gw, d_gw)));
        float sfp = RCP(1.f + EX2(fmaf(c, k_fp, d_fp)));
        float sol = RCP(1.f + EX2(fmaf(u2, k_ol, d_ol)));
        float oo = oo1 * soo, oogw = oogw1 * sgw, oofp = oofp1 * sfp, ol = ol1 * sol;
        float ratio = u2 * RCP(c);
        float olc = (c > 0.f) ? (ol - fmaxf(ol - ratio, 0.f)) : ol;
        float fg = 1.f - oo - oofp - oogw - olc;
        if (idx >= tl) c = fmaf(fg, c, u1 - px);
      }
    }
  }

  // ---- tail: t = WSPEC..WSPEC+7, buffer 14 columns x 8 in registers ----
  float vh[8], vhfp[8], vc[8], vl[8], vlc[8], vbp[8], vgw[8];
  float vib[8], voo[8], voofp[8], vol[8], volc[8], vf[8], voogw[8];
#pragma unroll
  for (int k = 0; k < 8; ++k) {
    const int idx = start + k;
    const int t = WSPEC + k;
    const int p = lb + t + (t >> 3);
    float u1 = su1[p], u2 = su2[p];
    float px = fmaxf(u1 + c - expC, 0.f);
    float iu = (u1 > 0.f) ? RCP(u1) : 0.f;
    float ib = px * iu;
    float soo = RCP(1.f + EX2(fmaf(c, k_oo, d_oo)));
    float sgw = RCP(1.f + EX2(fmaf(c, k_gw, d_gw)));
    float sfp = RCP(1.f + EX2(fmaf(c, k_fp, d_fp)));
    float sol = RCP(1.f + EX2(fmaf(u2, k_ol, d_ol)));
    float oo = oo1 * soo, oogw = oogw1 * sgw, oofp = oofp1 * sfp, ol = ol1 * sol;
    float ratio = u2 * RCP(c);
    float olc = (c > 0.f) ? (ol - fmaxf(ol - ratio, 0.f)) : ol;
    float fg = 1.f - oo - oofp - oogw - olc;
    bool act = idx >= tl;
    float m = act ? 1.f : 0.f;
    vh[k] = m * fmaf(oo, c, px);
    vhfp[k] = m * (oofp * c);
    vc[k] = m * c;                 // c0 entering this step
    vl[k] = m * (ol * c);
    vlc[k] = m * (olc * c);
    vbp[k] = m * px;
    vgw[k] = m * (oogw * c);
    vib[k] = m * ib;
    voo[k] = m * oo;
    voofp[k] = m * oofp;
    vol[k] = m * ol;
    volc[k] = m * olc;
    vf[k] = m * fg;
    voogw[k] = m * oogw;
    if (act) c = fmaf(fg, c, u1 - px);
  }

  // ---- flush: 2x float4 per column, direct from registers ----
  if (gid < NLANES) {
#define ST(col, v)                                                            \
  *(float4*)(out + (col) * NB + start) = make_float4(v[0], v[1], v[2], v[3]); \
  *(float4*)(out + (col) * NB + start + 4) = make_float4(v[4], v[5], v[6], v[7]);
    ST(0, vh) ST(1, vhfp) ST(2, vc) ST(3, vl) ST(4, vlc) ST(5, vbp) ST(6, vgw)
    ST(7, vib) ST(8, voo) ST(9, voofp) ST(10, vol) ST(11, volc) ST(12, vf)
    ST(13, voogw)
#undef ST
    // h_nout even slots (h part); odd slots owned by the std block
#pragma unroll
    for (int k = 0; k < 8; ++k)
      out[14 * NB + 2 * (start + k)] = vh[k];
  }
}

extern "C" void kernel_launch(void* const* d_in, const int* in_sizes, int n_in,
                              void* d_out, int out_size, void* d_ws, size_t ws_size,
                              hipStream_t stream) {
  const float* x        = (const float*)d_in[0];
  const float* y_obs    = (const float*)d_in[1];
  const float* p_mean   = (const float*)d_in[2];
  const float* p_std    = (const float*)d_in[3];
  // d_in[4] = epoch (unused by reference)
  const int* time_lag   = (const int*)d_in[5];
  const float* w_r_yom    = (const float*)d_in[6];
  const float* w_r_yom_fp = (const float*)d_in[7];
  const float* w_r_yom_gw = (const float*)d_in[8];
  const float* w_r_ylm    = (const float*)d_in[9];
  const float* w_r_yfm    = (const float*)d_in[10];
  const float* w_b1_yom   = (const float*)d_in[11];
  const float* w_b1_yom_gw= (const float*)d_in[12];
  const float* w_b1_yom_fp= (const float*)d_in[13];
  const float* w_b2_ylm   = (const float*)d_in[14];
  const float* theltaC    = (const float*)d_in[15];
  const float* b0_yom     = (const float*)d_in[16];
  const float* b0_yom_gw  = (const float*)d_in[17];
  const float* b0_yom_fp  = (const float*)d_in[18];
  const float* b0_ylm     = (const float*)d_in[19];
  float* out = (float*)d_out;
  (void)d_ws; (void)ws_size;

  fused_kernel<<<NSCANBLK + 1, 64, 0, stream>>>(
      x, y_obs, p_mean, p_std, time_lag,
      w_r_yom, w_r_yom_fp, w_r_yom_gw, w_r_ylm, w_r_yfm,
      w_b1_yom, w_b1_yom_gw, w_b1_yom_fp, w_b2_ylm,
      theltaC, b0_yom, b0_yom_gw, b0_yom_fp, b0_ylm,
      out);
}